// Round 12
// baseline (1730.786 us; speedup 1.0000x reference)
//
#include <hip/hip_runtime.h>
#include <hip/hip_bf16.h>

#define NN 50000
#define NE 800000
#define HD 128
#define DEPTH 5
#define NG 64
#define LNEPS 1e-5f

typedef __attribute__((ext_vector_type(8))) short bf8;   // 8 x bf16
typedef __attribute__((ext_vector_type(4))) float f4;

static __device__ __forceinline__ unsigned short bf1(float x) {
    __hip_bfloat16 b = __float2bfloat16(x);
    unsigned short r;
    __builtin_memcpy(&r, &b, 2);
    return r;
}
static __device__ __forceinline__ unsigned int cvt2(float a, float b) {
    float2 t; t.x = a; t.y = b;
    __hip_bfloat162 h = __float22bfloat162_rn(t);
    unsigned int r;
    __builtin_memcpy(&r, &h, 4);
    return r;
}

// p-space: p(n) = (n&15)*8 + (n>>4); pinv(p) = (p&7)*16 + (p>>3)

// ---------------------------------------------------------------------------
// Pack weights into bf16 MFMA B-fragment layouts.
// which==0: [W1d|W1s] K=128, 16 frag-cols, PINV rows (A comes from p-space LDS)
// which==1/3: K=128 GEMM2 mats, pinv rows.  which==2: upd_w1 K=256 straight.
// ---------------------------------------------------------------------------
__global__ void pack_weights(const float* __restrict__ msg_w1, const float* __restrict__ msg_w2,
                             const float* __restrict__ upd_w1, const float* __restrict__ upd_w2,
                             unsigned short* __restrict__ packed) {
    const int which = blockIdx.y & 3, layer = blockIdx.y >> 2;
    const int t = blockIdx.x * 256 + threadIdx.x;
    unsigned short* lbase = packed + layer * 98304;
    if (which == 0) {
        if (t >= 32768) return;
        const int e = t & 7, l = (t >> 3) & 63, f = (t >> 9) & 15, s = t >> 13;
        const int kk = s*32 + ((l >> 4) << 3) + e;
        const int k = (kk & 7)*16 + (kk >> 3);          // pinv
        const float* W = msg_w1 + layer*257*HD;
        const float v = (f < 8) ? W[k*HD + f*16 + (l & 15)]
                                : W[(k + 128)*HD + (f - 8)*16 + (l & 15)];
        lbase[t] = bf1(v);
        return;
    }
    const float* src; int K; unsigned short* dst;
    if (which == 1)      { src = msg_w2 + layer*HD*HD;  K = 128; dst = lbase + 32768; }
    else if (which == 2) { src = upd_w1 + layer*256*HD; K = 256; dst = lbase + 49152; }
    else                 { src = upd_w2 + layer*HD*HD;  K = 128; dst = lbase + 81920; }
    if (t >= K * HD) return;
    const int e = t & 7, l = (t >> 3) & 63, f = (t >> 9) & 7, s = t >> 12;
    const int kk = s*32 + ((l >> 4) << 3) + e;
    const int k = (which & 1) ? ((kk & 7)*16 + (kk >> 3)) : kk;
    const int n = f*16 + (l & 15);
    dst[t] = bf1(src[k*HD + n]);
}

// sigma-permuted per-layer edge constants: sig[layer*384 + {0:wl,1:g1,2:be1}*128 + i] = orig[pinv(i)]
__global__ void pack_sig(const float* __restrict__ msg_w1, const float* __restrict__ msg_g1,
                         const float* __restrict__ msg_be1, float* __restrict__ sig) {
    const int t = blockIdx.x * 256 + threadIdx.x;
    if (t >= DEPTH * 384) return;
    const int layer = t / 384, w3 = (t % 384) / 128, i = t % 128;
    const int col = (i & 7)*16 + (i >> 3);
    float v;
    if (w3 == 0)      v = msg_w1[layer*257*HD + 256*HD + col];
    else if (w3 == 1) v = msg_g1[layer*HD + col];
    else              v = msg_be1[layer*HD + col];
    sig[t] = v;
}

// rank-1 layer-0 y: A_sig/B_sig [256] s.t. y0[n][i] = x[n]*A[i] + B[i] (sigma space)
__global__ void pack_y0(const float* __restrict__ emb_w, const float* __restrict__ emb_b,
                        const float* __restrict__ msg_w1, const float* __restrict__ msg_b1,
                        float* __restrict__ y0ab) {
    const int t = threadIdx.x;                 // 256
    const int half = t >> 7, c = t & 127;
    const float* W = msg_w1 + half*128*HD;     // layer 0, d- or s-half rows
    float a = 0.f, b = 0.f;
    for (int k = 0; k < 128; ++k) {
        const float w = W[k*HD + c];
        a += emb_w[k] * w;
        b += emb_b[k] * w;
    }
    if (half == 0) b += msg_b1[c];
    const int i = half*128 + ((c & 15)*8 + (c >> 4));   // sigma position
    y0ab[i] = a; y0ab[256 + i] = b;
}

// embed: h = x*ew + eb (f32 + bf16) and y0 = x*A + B (bf16, sigma space)
__global__ void embed_kernel(const float* __restrict__ x, const float* __restrict__ emb_w,
                             const float* __restrict__ emb_b, const float* __restrict__ y0ab,
                             float* __restrict__ h, unsigned short* __restrict__ hb,
                             unsigned short* __restrict__ y) {
    const int i = blockIdx.x * 256 + threadIdx.x;      // NN*256 exact
    const int n = i >> 8, t = i & 255;
    const float xv = x[n];
    y[i] = bf1(xv * y0ab[t] + y0ab[256 + t]);
    if (t < 128) {
        const float v = xv * emb_w[t] + emb_b[t];
        h[n*HD + t] = v; hb[n*HD + t] = bf1(v);
    }
}

// --------------------- counting sort of edges by dst -----------------------
__global__ void hist_kernel(const int* __restrict__ ei, int* __restrict__ cnt) {
    const int e = blockIdx.x * 256 + threadIdx.x;      // NE exact
    atomicAdd(&cnt[ei[NE + e]], 1);
}

__global__ __launch_bounds__(1024) void scan_kernel(const int* __restrict__ cnt,
                                                    int* __restrict__ cur) {
    __shared__ int part[1024];
    const int t = threadIdx.x;
    const int per = 49;
    const int base = t * per;
    int s = 0;
    for (int i = 0; i < per; ++i) { const int idx = base + i; if (idx < NN) s += cnt[idx]; }
    part[t] = s; __syncthreads();
    for (int st = 1; st < 1024; st <<= 1) {
        const int v = (t >= st) ? part[t - st] : 0;
        __syncthreads();
        part[t] += v;
        __syncthreads();
    }
    int run = (t == 0) ? 0 : part[t - 1];
    for (int i = 0; i < per; ++i) {
        const int idx = base + i;
        if (idx < NN) { cur[idx] = run; run += cnt[idx]; }
    }
}

__global__ void scatter_kernel(const int* __restrict__ ei, int* __restrict__ cur,
                               int* __restrict__ sidx, int* __restrict__ ssrc,
                               int* __restrict__ sdst) {
    const int e = blockIdx.x * 256 + threadIdx.x;      // NE exact
    const int d = ei[NE + e];
    const int p = atomicAdd(&cur[d], 1);
    sidx[p] = e; ssrc[p] = ei[e]; sdst[p] = d;
}

__global__ void dist_kernel(const float* __restrict__ pos, const int* __restrict__ sidx,
                            const int* __restrict__ ssrc, const int* __restrict__ sdst,
                            const float* __restrict__ cell, const float* __restrict__ U,
                            float* __restrict__ dist) {
    const int p = blockIdx.x * 256 + threadIdx.x;      // NE exact
    const int e = sidx[p];
    const int s = ssrc[p], d = sdst[p];
    const float c0 = cell[e*3], c1 = cell[e*3+1], c2 = cell[e*3+2];
    const float ox = c0*U[0] + c1*U[3] + c2*U[6];
    const float oy = c0*U[1] + c1*U[4] + c2*U[7];
    const float oz = c0*U[2] + c1*U[5] + c2*U[8];
    const float dx = pos[d*3]   - ox - pos[s*3];
    const float dy = pos[d*3+1] - oy - pos[s*3+1];
    const float dz = pos[d*3+2] - oz - pos[s*3+2];
    dist[p] = sqrtf(dx*dx + dy*dy + dz*dz);
}

// ---------------------------------------------------------------------------
// Edge kernel: 64 edges/block, 256 threads = 4 waves. Phase 1: lane =
// (row l>>2, quarter l&3), msum[32], in-lane LN + 2 shfl. GEMM2: 4 waves x
// 16 rows. Segred: (col j, half hh), 32 serial rows. 8-slot XOR swizzle.
// ---------------------------------------------------------------------------
__global__ __launch_bounds__(256, 4) void edge_kernel(
    const unsigned short* __restrict__ y, const float* __restrict__ dist,
    const int* __restrict__ ssrc, const int* __restrict__ sdst,
    const unsigned short* __restrict__ pw2, const float* __restrict__ sig,
    const float* __restrict__ b2, const float* __restrict__ g2,
    const float* __restrict__ be2, float* __restrict__ aggr)
{
    __shared__ unsigned short lds[64 * 128];           // 16KB: t1/msg p-space
    __shared__ int dstl[64];
    char* ldsb = (char*)lds;
    const int tid = threadIdx.x, blk = blockIdx.x;
    const int l = tid & 63, wv = tid >> 6;             // 4 waves
    const int li = l & 15, gq = l >> 4;

    if (tid < 64) dstl[tid] = sdst[blk*64 + tid];

    // ---- phase 1: gather + LN1 + relu -> t1 (lane = row l>>2, quarter l&3) ----
    {
        const int rl = l >> 2, q = l & 3;
        const int row = wv*16 + rl;
        const int e = blk*64 + row;
        const int dn = sdst[e], sn = ssrc[e];
        const float dv = dist[e];
        const unsigned short* pd = y + dn*256 + q*32;
        const unsigned short* pS = y + sn*256 + 128 + q*32;
        const float* wl = sig + q*32;

        float msum[32];
        #pragma unroll
        for (int c = 0; c < 4; ++c) {
            const uint4 ud = *(const uint4*)(pd + c*8);
            const uint4 us = *(const uint4*)(pS + c*8);
            const float4 wa = *(const float4*)(wl + c*8);
            const float4 wb = *(const float4*)(wl + c*8 + 4);
            const unsigned int du[4] = {ud.x, ud.y, ud.z, ud.w};
            const unsigned int su[4] = {us.x, us.y, us.z, us.w};
            const float ww[8] = {wa.x,wa.y,wa.z,wa.w, wb.x,wb.y,wb.z,wb.w};
            #pragma unroll
            for (int k = 0; k < 4; ++k) {
                const float d0 = __uint_as_float(du[k] << 16);
                const float d1 = __uint_as_float(du[k] & 0xffff0000u);
                const float s0 = __uint_as_float(su[k] << 16);
                const float s1 = __uint_as_float(su[k] & 0xffff0000u);
                msum[c*8 + 2*k]     = d0 + s0 + dv*ww[2*k];
                msum[c*8 + 2*k + 1] = d1 + s1 + dv*ww[2*k+1];
            }
        }
        float s1 = 0.f, s2 = 0.f;
        #pragma unroll
        for (int i = 0; i < 32; ++i) { s1 += msum[i]; s2 += msum[i]*msum[i]; }
        s1 += __shfl_xor(s1, 1);  s2 += __shfl_xor(s2, 1);
        s1 += __shfl_xor(s1, 2);  s2 += __shfl_xor(s2, 2);
        const float mean = s1 * (1.f/HD);
        const float rstd = rsqrtf(s2*(1.f/HD) - mean*mean + LNEPS);

        const float* g1p = sig + 128 + q*32;
        const float* e1p = sig + 256 + q*32;
        const int rsw = (row & 7) << 4;
        const int base = row*256 + q*64;
        #pragma unroll
        for (int c = 0; c < 4; ++c) {
            const float4 ga = *(const float4*)(g1p + c*8);
            const float4 gb = *(const float4*)(g1p + c*8 + 4);
            const float4 ea = *(const float4*)(e1p + c*8);
            const float4 eb = *(const float4*)(e1p + c*8 + 4);
            const float gg[8] = {ga.x,ga.y,ga.z,ga.w, gb.x,gb.y,gb.z,gb.w};
            const float ee[8] = {ea.x,ea.y,ea.z,ea.w, eb.x,eb.y,eb.z,eb.w};
            float t[8];
            #pragma unroll
            for (int k = 0; k < 8; ++k)
                t[k] = fmaxf((msum[c*8+k] - mean)*rstd*gg[k] + ee[k], 0.f);
            uint4 u;
            u.x = cvt2(t[0], t[1]); u.y = cvt2(t[2], t[3]);
            u.z = cvt2(t[4], t[5]); u.w = cvt2(t[6], t[7]);
            *(uint4*)(ldsb + ((base + c*16) ^ rsw)) = u;
        }
    }
    // rows are wave-private: no barrier before GEMM2

    f4 acc2[8];
    #pragma unroll
    for (int f = 0; f < 8; ++f) { f4 z = {0.f,0.f,0.f,0.f}; acc2[f] = z; }
    #pragma unroll
    for (int s = 0; s < 4; ++s) {
        bf8 breg[8];
        #pragma unroll
        for (int f = 0; f < 8; ++f) breg[f] = *(const bf8*)(pw2 + s*4096 + f*512 + l*8);
        const int ar = wv*16 + li;
        const bf8 a = *(const bf8*)(ldsb + ((ar*256 + s*64 + gq*16) ^ ((ar & 7) << 4)));
        #pragma unroll
        for (int f = 0; f < 8; ++f)
            acc2[f] = __builtin_amdgcn_mfma_f32_16x16x32_bf16(a, breg[f], acc2[f], 0, 0, 0);
    }

    // epilogue 2: +b2 -> LN -> relu -> b128 p-space msg write
    {
        float bb2[8], gg2[8], be2v[8];
        #pragma unroll
        for (int f = 0; f < 8; ++f) {
            const int n = f*16 + li;
            bb2[f] = b2[n]; gg2[f] = g2[n]; be2v[f] = be2[n];
        }
        float ps[4] = {0,0,0,0}, pq[4] = {0,0,0,0};
        #pragma unroll
        for (int f = 0; f < 8; ++f)
            #pragma unroll
            for (int r = 0; r < 4; ++r) {
                const float v = acc2[f][r] + bb2[f];
                acc2[f][r] = v;
                ps[r] += v; pq[r] += v*v;
            }
        #pragma unroll
        for (int mm = 1; mm < 16; mm <<= 1)
            #pragma unroll
            for (int r = 0; r < 4; ++r) {
                ps[r] += __shfl_xor(ps[r], mm);
                pq[r] += __shfl_xor(pq[r], mm);
            }
        #pragma unroll
        for (int r = 0; r < 4; ++r) {
            const float mean = ps[r] * (1.f/HD);
            const float rstd = rsqrtf(pq[r]*(1.f/HD) - mean*mean + LNEPS);
            const int row = wv*16 + gq*4 + r;
            float vv[8];
            #pragma unroll
            for (int f = 0; f < 8; ++f)
                vv[f] = fmaxf((acc2[f][r] - mean)*rstd*gg2[f] + be2v[f], 0.f);
            uint4 u;
            u.x = cvt2(vv[0], vv[1]); u.y = cvt2(vv[2], vv[3]);
            u.z = cvt2(vv[4], vv[5]); u.w = cvt2(vv[6], vv[7]);
            *(uint4*)(ldsb + ((row*256 + li*16) ^ ((row & 7) << 4))) = u;
        }
    }
    __syncthreads();

    // segmented reduce over 64 sorted rows: thread = (p-col j, half hh), 32 rows
    {
        const int j = tid & 127, hh = tid >> 7;
        const int jj = (j & 7)*16 + (j >> 3);          // original feature
        const int r0 = hh * 32;
        int curd = dstl[r0];
        float a0 = 0.f;
        #pragma unroll 4
        for (int i = 0; i < 32; ++i) {
            const int row = r0 + i;
            const int d = dstl[row];
            const unsigned short u = *(const unsigned short*)(ldsb + ((row*256 + j*2) ^ ((row & 7) << 4)));
            const float v = __uint_as_float(((unsigned int)u) << 16);
            if (d != curd) { unsafeAtomicAdd(&aggr[curd*HD + jj], a0); a0 = 0.f; curd = d; }
            a0 += v;
        }
        unsafeAtomicAdd(&aggr[curd*HD + jj], a0);
    }
}

// ---------------------------------------------------------------------------
// Node update + fused next-layer y. 64 nodes/block, 256 threads = 4 waves x 16.
// ---------------------------------------------------------------------------
__global__ __launch_bounds__(256, 4) void node_kernel(
    unsigned short* __restrict__ hb, float* __restrict__ aggr,
    const unsigned short* __restrict__ pw,
    const float* __restrict__ b1, const float* __restrict__ g1, const float* __restrict__ be1,
    const float* __restrict__ b2, const float* __restrict__ g2, const float* __restrict__ be2,
    float* __restrict__ h,
    const unsigned short* __restrict__ pwy, const float* __restrict__ b1y,
    unsigned short* __restrict__ y, int do_y)
{
    __shared__ unsigned short lds[64 * 128];
    char* ldsb = (char*)lds;
    const int tid = threadIdx.x, blk = blockIdx.x;
    const int l = tid & 63, wv = tid >> 6;             // 4 waves
    const int li = l & 15, gq = l >> 4;

    const int row = wv*16 + li;
    const int nA = blk*64 + row;
    const int nc = (nA < NN) ? nA : NN - 1;
    const unsigned short* pH = hb + nc*HD + gq*8;
    float* pA = aggr + nc*HD + gq*8;

    f4 acc[8];
    #pragma unroll
    for (int f = 0; f < 8; ++f) { f4 z = {0.f,0.f,0.f,0.f}; acc[f] = z; }

    #pragma unroll
    for (int s = 0; s < 8; ++s) {
        bf8 breg[8];
        #pragma unroll
        for (int f = 0; f < 8; ++f) breg[f] = *(const bf8*)(pw + s*4096 + f*512 + l*8);
        bf8 a;
        if (s < 4) {
            a = *(const bf8*)(pH + s*32);
        } else {
            const float4 a0 = *(const float4*)(pA + (s-4)*32);
            const float4 a1 = *(const float4*)(pA + (s-4)*32 + 4);
            union { unsigned int u[4]; bf8 v; } pk;
            pk.u[0] = cvt2(a0.x, a0.y); pk.u[1] = cvt2(a0.z, a0.w);
            pk.u[2] = cvt2(a1.x, a1.y); pk.u[3] = cvt2(a1.z, a1.w);
            a = pk.v;
        }
        #pragma unroll
        for (int f = 0; f < 8; ++f)
            acc[f] = __builtin_amdgcn_mfma_f32_16x16x32_bf16(a, breg[f], acc[f], 0, 0, 0);
    }

    // zero aggr slices for next layer
    {
        const float4 z = {0.f,0.f,0.f,0.f};
        if (nA < NN) {
            #pragma unroll
            for (int s = 0; s < 4; ++s) { *(float4*)(pA + s*32) = z; *(float4*)(pA + s*32 + 4) = z; }
        }
    }

    // epilogue 1 -> p-space t1
    {
        float bb[8], gg[8], be[8];
        #pragma unroll
        for (int f = 0; f < 8; ++f) {
            const int n = f*16 + li;
            bb[f] = b1[n]; gg[f] = g1[n]; be[f] = be1[n];
        }
        float ps[4] = {0,0,0,0}, pq[4] = {0,0,0,0};
        #pragma unroll
        for (int f = 0; f < 8; ++f)
            #pragma unroll
            for (int r = 0; r < 4; ++r) {
                const float v = acc[f][r] + bb[f];
                acc[f][r] = v;
                ps[r] += v; pq[r] += v*v;
            }
        #pragma unroll
        for (int mm = 1; mm < 16; mm <<= 1)
            #pragma unroll
            for (int r = 0; r < 4; ++r) {
                ps[r] += __shfl_xor(ps[r], mm);
                pq[r] += __shfl_xor(pq[r], mm);
            }
        #pragma unroll
        for (int r = 0; r < 4; ++r) {
            const float mean = ps[r] * (1.f/HD);
            const float rstd = rsqrtf(pq[r]*(1.f/HD) - mean*mean + LNEPS);
            const int rw = wv*16 + gq*4 + r;
            float vv[8];
            #pragma unroll
            for (int f = 0; f < 8; ++f)
                vv[f] = fmaxf((acc[f][r] - mean)*rstd*gg[f] + be[f], 0.f);
            uint4 u;
            u.x = cvt2(vv[0], vv[1]); u.y = cvt2(vv[2], vv[3]);
            u.z = cvt2(vv[4], vv[5]); u.w = cvt2(vv[6], vv[7]);
            *(uint4*)(ldsb + ((rw*256 + li*16) ^ ((rw & 15) << 4))) = u;
        }
    }
    // wave-private rows: no barrier

    const unsigned short* pw2 = pw + 32768;
    f4 acc2[8];
    #pragma unroll
    for (int f = 0; f < 8; ++f) { f4 z = {0.f,0.f,0.f,0.f}; acc2[f] = z; }
    #pragma unroll
    for (int s = 0; s < 4; ++s) {
        bf8 breg[8];
        #pragma unroll
        for (int f = 0; f < 8; ++f) breg[f] = *(const bf8*)(pw2 + s*4096 + f*512 + l*8);
        const int ar = wv*16 + li;
        const bf8 a = *(const bf8*)(ldsb + ((ar*256 + s*64 + gq*16) ^ ((ar & 15) << 4)));
        #pragma unroll
        for (int f = 0; f < 8; ++f)
            acc2[f] = __builtin_amdgcn_mfma_f32_16x16x32_bf16(a, breg[f], acc2[f], 0, 0, 0);
    }

    // epilogue 2: LN -> relu -> nh = h + u (global h/hb + p-space LDS for y-GEMM)
    {
        float bb2[8], gg2[8], be2v[8];
        #pragma unroll
        for (int f = 0; f < 8; ++f) {
            const int n = f*16 + li;
            bb2[f] = b2[n]; gg2[f] = g2[n]; be2v[f] = be2[n];
        }
        float ps[4] = {0,0,0,0}, pq[4] = {0,0,0,0};
        #pragma unroll
        for (int f = 0; f < 8; ++f)
            #pragma unroll
            for (int r = 0; r < 4; ++r) {
                const float v = acc2[f][r] + bb2[f];
                acc2[f][r] = v;
                ps[r] += v; pq[r] += v*v;
            }
        #pragma unroll
        for (int mm = 1; mm < 16; mm <<= 1)
            #pragma unroll
            for (int r = 0; r < 4; ++r) {
                ps[r] += __shfl_xor(ps[r], mm);
                pq[r] += __shfl_xor(pq[r], mm);
            }
        #pragma unroll
        for (int r = 0; r < 4; ++r) {
            const int node = blk*64 + wv*16 + gq*4 + r;
            const float mean = ps[r] * (1.f/HD);
            const float rstd = rsqrtf(pq[r]*(1.f/HD) - mean*mean + LNEPS);
            const int rw = wv*16 + gq*4 + r;
            float nhv[8];
            if (node < NN) {
                #pragma unroll
                for (int f = 0; f < 8; ++f) {
                    const int n = f*16 + li;
                    float v = fmaxf((acc2[f][r] - mean)*rstd*gg2[f] + be2v[f], 0.f);
                    const int idx = node*HD + n;
                    const float nh = h[idx] + v;
                    h[idx] = nh; hb[idx] = bf1(nh);
                    nhv[f] = nh;
                }
            } else {
                #pragma unroll
                for (int f = 0; f < 8; ++f) nhv[f] = 0.f;
            }
            uint4 u;
            u.x = cvt2(nhv[0], nhv[1]); u.y = cvt2(nhv[2], nhv[3]);
            u.z = cvt2(nhv[4], nhv[5]); u.w = cvt2(nhv[6], nhv[7]);
            *(uint4*)(ldsb + ((rw*256 + li*16) ^ ((rw & 15) << 4))) = u;
        }
    }

    // fused y-GEMM for next layer: A = nh p-space LDS, B = pinv-packed [W1d|W1s]
    if (do_y) {
        f4 accy[16];
        #pragma unroll
        for (int f = 0; f < 16; ++f) { f4 z = {0.f,0.f,0.f,0.f}; accy[f] = z; }
        #pragma unroll
        for (int s = 0; s < 4; ++s) {
            const int ar = wv*16 + li;
            const bf8 a = *(const bf8*)(ldsb + ((ar*256 + s*64 + gq*16) ^ ((ar & 15) << 4)));
            #pragma unroll
            for (int fh = 0; fh < 2; ++fh) {
                bf8 breg[8];
                #pragma unroll
                for (int f = 0; f < 8; ++f)
                    breg[f] = *(const bf8*)(pwy + s*8192 + (fh*8 + f)*512 + l*8);
                #pragma unroll
                for (int f = 0; f < 8; ++f)
                    accy[fh*8 + f] = __builtin_amdgcn_mfma_f32_16x16x32_bf16(a, breg[f], accy[fh*8 + f], 0, 0, 0);
            }
        }
        float bv[8];
        #pragma unroll
        for (int f = 0; f < 8; ++f) bv[f] = b1y[f*16 + li];
        #pragma unroll
        for (int r = 0; r < 4; ++r) {
            const int node = blk*64 + wv*16 + gq*4 + r;
            if (node < NN) {
                uint4 u;
                u.x = cvt2(accy[0][r]+bv[0], accy[1][r]+bv[1]);
                u.y = cvt2(accy[2][r]+bv[2], accy[3][r]+bv[3]);
                u.z = cvt2(accy[4][r]+bv[4], accy[5][r]+bv[5]);
                u.w = cvt2(accy[6][r]+bv[6], accy[7][r]+bv[7]);
                *(uint4*)(y + node*256 + li*8) = u;
                uint4 v;
                v.x = cvt2(accy[8][r],  accy[9][r]);
                v.y = cvt2(accy[10][r], accy[11][r]);
                v.z = cvt2(accy[12][r], accy[13][r]);
                v.w = cvt2(accy[14][r], accy[15][r]);
                *(uint4*)(y + node*256 + 128 + li*8) = v;
            }
        }
    }
}

// global_add_pool over sorted batch_ids
__global__ void pool_kernel(const float* __restrict__ h, const int* __restrict__ bids,
                            float* __restrict__ pooled) {
    const int j = threadIdx.x;                  // 128 features
    const int n0 = blockIdx.x * 256;
    if (n0 >= NN) return;
    int cur = bids[n0];
    float acc = 0.f;
    for (int i = 0; i < 256; ++i) {
        const int n = n0 + i;
        if (n >= NN) break;
        const int b = bids[n];
        if (b != cur) { unsafeAtomicAdd(&pooled[cur*HD + j], acc); acc = 0.f; cur = b; }
        acc += h[n*HD + j];
    }
    unsafeAtomicAdd(&pooled[cur*HD + j], acc);
}

__global__ void pred_kernel(const float* __restrict__ pooled, const float* __restrict__ w1,
                            const float* __restrict__ pb1, const float* __restrict__ w2,
                            const float* __restrict__ pb2, float* __restrict__ out) {
    const int g = blockIdx.x, j = threadIdx.x;  // 128 threads
    __shared__ float pg[128];
    __shared__ float red[128];
    pg[j] = pooled[g*HD + j];
    __syncthreads();
    float z = pb1[j];
    for (int k = 0; k < 128; ++k) z += pg[k] * w1[k*HD + j];
    red[j] = fmaxf(z, 0.f) * w2[j];
    __syncthreads();
    for (int st = 64; st > 0; st >>= 1) {
        if (j < st) red[j] += red[j + st];
        __syncthreads();
    }
    if (j == 0) out[g] = red[0] + pb2[0];
}

extern "C" void kernel_launch(void* const* d_in, const int* in_sizes, int n_in,
                              void* d_out, int out_size, void* d_ws, size_t ws_size,
                              hipStream_t stream) {
    const float* x       = (const float*)d_in[0];
    const float* pos     = (const float*)d_in[1];
    const int*   ei      = (const int*)  d_in[2];
    const float* cell    = (const float*)d_in[3];
    const float* U       = (const float*)d_in[4];
    const int*   bids    = (const int*)  d_in[5];
    const float* emb_w   = (const float*)d_in[6];
    const float* emb_b   = (const float*)d_in[7];
    const float* msg_w1  = (const float*)d_in[8];
    const float* msg_b1  = (const float*)d_in[9];
    const float* msg_g1  = (const float*)d_in[10];
    const float* msg_be1 = (const float*)d_in[11];
    const float* msg_w2  = (const float*)d_in[12];
    const float* msg_b2  = (const float*)d_in[13];
    const float* msg_g2  = (const float*)d_in[14];
    const float* msg_be2 = (const float*)d_in[15];
    const float* upd_w1  = (const float*)d_in[16];
    const float* upd_b1  = (const float*)d_in[17];
    const float* upd_g1  = (const float*)d_in[18];
    const float* upd_be1 = (const float*)d_in[19];
    const float* upd_w2  = (const float*)d_in[20];
    const float* upd_b2  = (const float*)d_in[21];
    const float* upd_g2  = (const float*)d_in[22];
    const float* upd_be2 = (const float*)d_in[23];
    const float* pred_w1 = (const float*)d_in[24];
    const float* pred_b1 = (const float*)d_in[25];
    const float* pred_w2 = (const float*)d_in[26];
    const float* pred_b2 = (const float*)d_in[27];

    char* ws = (char*)d_ws;
    float*          h      = (float*)          ws;                 // 25,600,000
    unsigned short* hb     = (unsigned short*)(ws + 25600000);     // 12,800,000
    float*          aggr   = (float*)         (ws + 38400000);     // 25,600,000
    float*          dist   = (float*)         (ws + 64000000);     //  3,200,000
    float*          pooled = (float*)         (ws + 67200000);     //     32,768
    unsigned short* packed = (unsigned short*)(ws + 67232768);     //    983,040
    int*            cnt    = (int*)           (ws + 68215808);     //    200,704
    int*            cur    = (int*)           (ws + 68416512);     //    200,704
    int*            sidx   = (int*)           (ws + 68617216);     //  3,200,000
    int*            ssrc   = (int*)           (ws + 71817216);     //  3,200,000
    int*            sdst   = (int*)           (ws + 75017216);     //  3,200,000
    float*          sig    = (float*)         (ws + 78217216);     //      7,680
    float*          y0ab   = (float*)         (ws + 78224896);     //      2,048
    unsigned short* y      = (unsigned short*)(ws + 78226944);     // 25,600,000

    hipMemsetAsync(aggr, 0, (size_t)NN * HD * sizeof(float), stream);
    hipMemsetAsync(pooled, 0, (size_t)NG * HD * sizeof(float), stream);
    hipMemsetAsync(cnt, 0, (size_t)NN * sizeof(int), stream);

    dim3 pgrid(128, DEPTH * 4);
    pack_weights<<<pgrid, 256, 0, stream>>>(msg_w1, msg_w2, upd_w1, upd_w2, packed);
    pack_sig<<<(DEPTH*384 + 255)/256, 256, 0, stream>>>(msg_w1, msg_g1, msg_be1, sig);
    pack_y0<<<1, 256, 0, stream>>>(emb_w, emb_b, msg_w1, msg_b1, y0ab);
    embed_kernel<<<NN, 256, 0, stream>>>(x, emb_w, emb_b, y0ab, h, hb, y);

    hist_kernel<<<NE / 256, 256, 0, stream>>>(ei, cnt);
    scan_kernel<<<1, 1024, 0, stream>>>(cnt, cur);
    scatter_kernel<<<NE / 256, 256, 0, stream>>>(ei, cur, sidx, ssrc, sdst);
    dist_kernel<<<NE / 256, 256, 0, stream>>>(pos, sidx, ssrc, sdst, cell, U, dist);

    for (int layer = 0; layer < DEPTH; ++layer) {
        const unsigned short* pl = packed + layer * 98304;
        edge_kernel<<<NE / 64, 256, 0, stream>>>(
            y, dist, ssrc, sdst, pl + 32768, sig + layer*384,
            msg_b2 + layer*HD, msg_g2 + layer*HD, msg_be2 + layer*HD,
            aggr);
        const int do_y = (layer + 1 < DEPTH) ? 1 : 0;
        const int nl = do_y ? layer + 1 : layer;
        node_kernel<<<(NN + 63) / 64, 256, 0, stream>>>(
            hb, aggr, pl + 49152,
            upd_b1 + layer*HD, upd_g1 + layer*HD, upd_be1 + layer*HD,
            upd_b2 + layer*HD, upd_g2 + layer*HD, upd_be2 + layer*HD,
            h,
            packed + nl * 98304, msg_b1 + nl*HD, y, do_y);
    }

    pool_kernel<<<(NN + 255) / 256, 128, 0, stream>>>(h, bids, pooled);
    pred_kernel<<<NG, 128, 0, stream>>>(pooled, pred_w1, pred_b1, pred_w2, pred_b2, (float*)d_out);
}

// Round 13
// 1320.078 us; speedup vs baseline: 1.3111x; 1.3111x over previous
//
#include <hip/hip_runtime.h>
#include <hip/hip_bf16.h>

#define NN 50000
#define NE 800000
#define HD 128
#define DEPTH 5
#define NG 64
#define LNEPS 1e-5f

typedef __attribute__((ext_vector_type(8))) short bf8;   // 8 x bf16
typedef __attribute__((ext_vector_type(4))) float f4;

static __device__ __forceinline__ unsigned short bf1(float x) {
    __hip_bfloat16 b = __float2bfloat16(x);
    unsigned short r;
    __builtin_memcpy(&r, &b, 2);
    return r;
}
static __device__ __forceinline__ unsigned int cvt2(float a, float b) {
    float2 t; t.x = a; t.y = b;
    __hip_bfloat162 h = __float22bfloat162_rn(t);
    unsigned int r;
    __builtin_memcpy(&r, &h, 4);
    return r;
}

// p-space: p(n) = (n&15)*8 + (n>>4); pinv(p) = (p&7)*16 + (p>>3)

// ---------------------------------------------------------------------------
// Pack weights into bf16 MFMA B-fragment layouts.
// which==0: [W1d|W1s] K=128, 16 frag-cols, PINV rows (A comes from p-space LDS)
// which==1/3: K=128 GEMM2 mats, pinv rows.  which==2: upd_w1 K=256 straight.
// ---------------------------------------------------------------------------
__global__ void pack_weights(const float* __restrict__ msg_w1, const float* __restrict__ msg_w2,
                             const float* __restrict__ upd_w1, const float* __restrict__ upd_w2,
                             unsigned short* __restrict__ packed) {
    const int which = blockIdx.y & 3, layer = blockIdx.y >> 2;
    const int t = blockIdx.x * 256 + threadIdx.x;
    unsigned short* lbase = packed + layer * 98304;
    if (which == 0) {
        if (t >= 32768) return;
        const int e = t & 7, l = (t >> 3) & 63, f = (t >> 9) & 15, s = t >> 13;
        const int kk = s*32 + ((l >> 4) << 3) + e;
        const int k = (kk & 7)*16 + (kk >> 3);          // pinv
        const float* W = msg_w1 + layer*257*HD;
        const float v = (f < 8) ? W[k*HD + f*16 + (l & 15)]
                                : W[(k + 128)*HD + (f - 8)*16 + (l & 15)];
        lbase[t] = bf1(v);
        return;
    }
    const float* src; int K; unsigned short* dst;
    if (which == 1)      { src = msg_w2 + layer*HD*HD;  K = 128; dst = lbase + 32768; }
    else if (which == 2) { src = upd_w1 + layer*256*HD; K = 256; dst = lbase + 49152; }
    else                 { src = upd_w2 + layer*HD*HD;  K = 128; dst = lbase + 81920; }
    if (t >= K * HD) return;
    const int e = t & 7, l = (t >> 3) & 63, f = (t >> 9) & 7, s = t >> 12;
    const int kk = s*32 + ((l >> 4) << 3) + e;
    const int k = (which & 1) ? ((kk & 7)*16 + (kk >> 3)) : kk;
    const int n = f*16 + (l & 15);
    dst[t] = bf1(src[k*HD + n]);
}

// sigma-permuted per-layer edge constants: sig[layer*384 + {0:wl,1:g1,2:be1}*128 + i] = orig[pinv(i)]
__global__ void pack_sig(const float* __restrict__ msg_w1, const float* __restrict__ msg_g1,
                         const float* __restrict__ msg_be1, float* __restrict__ sig) {
    const int t = blockIdx.x * 256 + threadIdx.x;
    if (t >= DEPTH * 384) return;
    const int layer = t / 384, w3 = (t % 384) / 128, i = t % 128;
    const int col = (i & 7)*16 + (i >> 3);
    float v;
    if (w3 == 0)      v = msg_w1[layer*257*HD + 256*HD + col];
    else if (w3 == 1) v = msg_g1[layer*HD + col];
    else              v = msg_be1[layer*HD + col];
    sig[t] = v;
}

// rank-1 layer-0 y: A_sig/B_sig [256] s.t. y0[n][i] = x[n]*A[i] + B[i] (sigma space)
__global__ void pack_y0(const float* __restrict__ emb_w, const float* __restrict__ emb_b,
                        const float* __restrict__ msg_w1, const float* __restrict__ msg_b1,
                        float* __restrict__ y0ab) {
    const int t = threadIdx.x;                 // 256
    const int half = t >> 7, c = t & 127;
    const float* W = msg_w1 + half*128*HD;     // layer 0, d- or s-half rows
    float a = 0.f, b = 0.f;
    for (int k = 0; k < 128; ++k) {
        const float w = W[k*HD + c];
        a += emb_w[k] * w;
        b += emb_b[k] * w;
    }
    if (half == 0) b += msg_b1[c];
    const int i = half*128 + ((c & 15)*8 + (c >> 4));   // sigma position
    y0ab[i] = a; y0ab[256 + i] = b;
}

// embed: h = x*ew + eb (f32 + bf16) and y0 = x*A + B (bf16, sigma space)
__global__ void embed_kernel(const float* __restrict__ x, const float* __restrict__ emb_w,
                             const float* __restrict__ emb_b, const float* __restrict__ y0ab,
                             float* __restrict__ h, unsigned short* __restrict__ hb,
                             unsigned short* __restrict__ y) {
    const int i = blockIdx.x * 256 + threadIdx.x;      // NN*256 exact
    const int n = i >> 8, t = i & 255;
    const float xv = x[n];
    y[i] = bf1(xv * y0ab[t] + y0ab[256 + t]);
    if (t < 128) {
        const float v = xv * emb_w[t] + emb_b[t];
        h[n*HD + t] = v; hb[n*HD + t] = bf1(v);
    }
}

// --------------------- counting sort of edges by dst -----------------------
__global__ void hist_kernel(const int* __restrict__ ei, int* __restrict__ cnt) {
    const int e = blockIdx.x * 256 + threadIdx.x;      // NE exact
    atomicAdd(&cnt[ei[NE + e]], 1);
}

__global__ __launch_bounds__(1024) void scan_kernel(const int* __restrict__ cnt,
                                                    int* __restrict__ cur) {
    __shared__ int part[1024];
    const int t = threadIdx.x;
    const int per = 49;
    const int base = t * per;
    int s = 0;
    for (int i = 0; i < per; ++i) { const int idx = base + i; if (idx < NN) s += cnt[idx]; }
    part[t] = s; __syncthreads();
    for (int st = 1; st < 1024; st <<= 1) {
        const int v = (t >= st) ? part[t - st] : 0;
        __syncthreads();
        part[t] += v;
        __syncthreads();
    }
    int run = (t == 0) ? 0 : part[t - 1];
    for (int i = 0; i < per; ++i) {
        const int idx = base + i;
        if (idx < NN) { cur[idx] = run; run += cnt[idx]; }
    }
}

__global__ void scatter_kernel(const int* __restrict__ ei, int* __restrict__ cur,
                               int* __restrict__ sidx, int* __restrict__ ssrc,
                               int* __restrict__ sdst) {
    const int e = blockIdx.x * 256 + threadIdx.x;      // NE exact
    const int d = ei[NE + e];
    const int p = atomicAdd(&cur[d], 1);
    sidx[p] = e; ssrc[p] = ei[e]; sdst[p] = d;
}

__global__ void dist_kernel(const float* __restrict__ pos, const int* __restrict__ sidx,
                            const int* __restrict__ ssrc, const int* __restrict__ sdst,
                            const float* __restrict__ cell, const float* __restrict__ U,
                            float* __restrict__ dist) {
    const int p = blockIdx.x * 256 + threadIdx.x;      // NE exact
    const int e = sidx[p];
    const int s = ssrc[p], d = sdst[p];
    const float c0 = cell[e*3], c1 = cell[e*3+1], c2 = cell[e*3+2];
    const float ox = c0*U[0] + c1*U[3] + c2*U[6];
    const float oy = c0*U[1] + c1*U[4] + c2*U[7];
    const float oz = c0*U[2] + c1*U[5] + c2*U[8];
    const float dx = pos[d*3]   - ox - pos[s*3];
    const float dy = pos[d*3+1] - oy - pos[s*3+1];
    const float dz = pos[d*3+2] - oz - pos[s*3+2];
    dist[p] = sqrtf(dx*dx + dy*dy + dz*dz);
}

// ---------------------------------------------------------------------------
// Edge kernel (R11-exact): gather yd[dst]+ys[src]+dist*wl -> LN1 -> relu ->
// t1 p-space LDS -> GEMM2 -> LN2 -> relu -> msg p-space -> per-col segred.
// 64 edges/block, 128 threads, 2 waves x 32 rows, 8-slot XOR swizzle.
// ---------------------------------------------------------------------------
__global__ __launch_bounds__(128, 4) void edge_kernel(
    const unsigned short* __restrict__ y, const float* __restrict__ dist,
    const int* __restrict__ ssrc, const int* __restrict__ sdst,
    const unsigned short* __restrict__ pw2, const float* __restrict__ sig,
    const float* __restrict__ b2, const float* __restrict__ g2,
    const float* __restrict__ be2, float* __restrict__ aggr)
{
    __shared__ unsigned short lds[64 * 128];           // 16KB: t1/msg p-space
    __shared__ int dstl[64];
    char* ldsb = (char*)lds;
    const int tid = threadIdx.x, blk = blockIdx.x;
    const int l = tid & 63, wv = tid >> 6;
    const int li = l & 15, gq = l >> 4;

    if (tid < 64) dstl[tid] = sdst[blk*64 + tid];

    // ---- phase 1: gather + LN1 + relu -> t1 (lane = row l>>1, half l&1) ----
    {
        const int rl = l >> 1, half = l & 1;
        const int row = wv*32 + rl;
        const int e = blk*64 + row;
        const int dn = sdst[e], sn = ssrc[e];
        const float dv = dist[e];
        const unsigned short* pd = y + dn*256 + half*64;
        const unsigned short* pS = y + sn*256 + 128 + half*64;
        const float* wl = sig + half*64;

        float msum[64];
        #pragma unroll
        for (int c = 0; c < 8; ++c) {
            const uint4 ud = *(const uint4*)(pd + c*8);
            const uint4 us = *(const uint4*)(pS + c*8);
            const float4 wa = *(const float4*)(wl + c*8);
            const float4 wb = *(const float4*)(wl + c*8 + 4);
            const unsigned int du[4] = {ud.x, ud.y, ud.z, ud.w};
            const unsigned int su[4] = {us.x, us.y, us.z, us.w};
            const float ww[8] = {wa.x,wa.y,wa.z,wa.w, wb.x,wb.y,wb.z,wb.w};
            #pragma unroll
            for (int k = 0; k < 4; ++k) {
                const float d0 = __uint_as_float(du[k] << 16);
                const float d1 = __uint_as_float(du[k] & 0xffff0000u);
                const float s0 = __uint_as_float(su[k] << 16);
                const float s1 = __uint_as_float(su[k] & 0xffff0000u);
                msum[c*8 + 2*k]     = d0 + s0 + dv*ww[2*k];
                msum[c*8 + 2*k + 1] = d1 + s1 + dv*ww[2*k+1];
            }
        }
        float s1 = 0.f, s2 = 0.f;
        #pragma unroll
        for (int i = 0; i < 64; ++i) { s1 += msum[i]; s2 += msum[i]*msum[i]; }
        s1 += __shfl_xor(s1, 1);
        s2 += __shfl_xor(s2, 1);
        const float mean = s1 * (1.f/HD);
        const float rstd = rsqrtf(s2*(1.f/HD) - mean*mean + LNEPS);

        const float* g1p = sig + 128 + half*64;
        const float* e1p = sig + 256 + half*64;
        const int rsw = (row & 7) << 4;
        const int base = row*256 + half*128;
        #pragma unroll
        for (int c = 0; c < 8; ++c) {
            const float4 ga = *(const float4*)(g1p + c*8);
            const float4 gb = *(const float4*)(g1p + c*8 + 4);
            const float4 ea = *(const float4*)(e1p + c*8);
            const float4 eb = *(const float4*)(e1p + c*8 + 4);
            const float gg[8] = {ga.x,ga.y,ga.z,ga.w, gb.x,gb.y,gb.z,gb.w};
            const float ee[8] = {ea.x,ea.y,ea.z,ea.w, eb.x,eb.y,eb.z,eb.w};
            float t[8];
            #pragma unroll
            for (int k = 0; k < 8; ++k)
                t[k] = fmaxf((msum[c*8+k] - mean)*rstd*gg[k] + ee[k], 0.f);
            uint4 u;
            u.x = cvt2(t[0], t[1]); u.y = cvt2(t[2], t[3]);
            u.z = cvt2(t[4], t[5]); u.w = cvt2(t[6], t[7]);
            *(uint4*)(ldsb + ((base + c*16) ^ rsw)) = u;
        }
    }
    // rows are wave-private: no barrier before GEMM2

    f4 acc2[2][8];
    #pragma unroll
    for (int m = 0; m < 2; ++m)
        #pragma unroll
        for (int f = 0; f < 8; ++f) { f4 z = {0.f,0.f,0.f,0.f}; acc2[m][f] = z; }
    #pragma unroll
    for (int s = 0; s < 4; ++s) {
        bf8 breg[8];
        #pragma unroll
        for (int f = 0; f < 8; ++f) breg[f] = *(const bf8*)(pw2 + s*4096 + f*512 + l*8);
        #pragma unroll
        for (int m = 0; m < 2; ++m) {
            const int ar = wv*32 + m*16 + li;
            const bf8 a = *(const bf8*)(ldsb + ((ar*256 + s*64 + gq*16) ^ ((ar & 7) << 4)));
            #pragma unroll
            for (int f = 0; f < 8; ++f)
                acc2[m][f] = __builtin_amdgcn_mfma_f32_16x16x32_bf16(a, breg[f], acc2[m][f], 0, 0, 0);
        }
    }

    // epilogue 2: +b2 -> LN -> relu -> b128 p-space msg write
    {
        float bb2[8], gg2[8], be2v[8];
        #pragma unroll
        for (int f = 0; f < 8; ++f) {
            const int n = f*16 + li;
            bb2[f] = b2[n]; gg2[f] = g2[n]; be2v[f] = be2[n];
        }
        #pragma unroll
        for (int m = 0; m < 2; ++m) {
            float ps[4] = {0,0,0,0}, pq[4] = {0,0,0,0};
            #pragma unroll
            for (int f = 0; f < 8; ++f)
                #pragma unroll
                for (int r = 0; r < 4; ++r) {
                    const float v = acc2[m][f][r] + bb2[f];
                    acc2[m][f][r] = v;
                    ps[r] += v; pq[r] += v*v;
                }
            #pragma unroll
            for (int mm = 1; mm < 16; mm <<= 1)
                #pragma unroll
                for (int r = 0; r < 4; ++r) {
                    ps[r] += __shfl_xor(ps[r], mm);
                    pq[r] += __shfl_xor(pq[r], mm);
                }
            #pragma unroll
            for (int r = 0; r < 4; ++r) {
                const float mean = ps[r] * (1.f/HD);
                const float rstd = rsqrtf(pq[r]*(1.f/HD) - mean*mean + LNEPS);
                const int row = wv*32 + m*16 + gq*4 + r;
                float vv[8];
                #pragma unroll
                for (int f = 0; f < 8; ++f)
                    vv[f] = fmaxf((acc2[m][f][r] - mean)*rstd*gg2[f] + be2v[f], 0.f);
                uint4 u;
                u.x = cvt2(vv[0], vv[1]); u.y = cvt2(vv[2], vv[3]);
                u.z = cvt2(vv[4], vv[5]); u.w = cvt2(vv[6], vv[7]);
                *(uint4*)(ldsb + ((row*256 + li*16) ^ ((row & 7) << 4))) = u;
            }
        }
    }
    __syncthreads();

    // segmented reduce over 64 sorted rows: one thread per p-col
    {
        const int j = tid;                              // 0..127
        const int jj = (j & 7)*16 + (j >> 3);          // original feature
        int curd = dstl[0];
        float a0 = 0.f;
        #pragma unroll 4
        for (int row = 0; row < 64; ++row) {
            const int d = dstl[row];
            const unsigned short u = *(const unsigned short*)(ldsb + ((row*256 + j*2) ^ ((row & 7) << 4)));
            const float v = __uint_as_float(((unsigned int)u) << 16);
            if (d != curd) { unsafeAtomicAdd(&aggr[curd*HD + jj], a0); a0 = 0.f; curd = d; }
            a0 += v;
        }
        unsafeAtomicAdd(&aggr[curd*HD + jj], a0);
    }
}

// ---------------------------------------------------------------------------
// Node update + fused next-layer y. 32 nodes/block, 128 threads = 2 waves x 16
// rows (small-grid residency fix: 1563 blocks ~ 6/CU). Zeroes aggr in-place.
// ---------------------------------------------------------------------------
__global__ __launch_bounds__(128, 4) void node_kernel(
    unsigned short* __restrict__ hb, float* __restrict__ aggr,
    const unsigned short* __restrict__ pw,
    const float* __restrict__ b1, const float* __restrict__ g1, const float* __restrict__ be1,
    const float* __restrict__ b2, const float* __restrict__ g2, const float* __restrict__ be2,
    float* __restrict__ h,
    const unsigned short* __restrict__ pwy, const float* __restrict__ b1y,
    unsigned short* __restrict__ y, int do_y)
{
    __shared__ unsigned short lds[32 * 128];           // 8KB
    char* ldsb = (char*)lds;
    const int tid = threadIdx.x, blk = blockIdx.x;
    const int l = tid & 63, wv = tid >> 6;             // 2 waves
    const int li = l & 15, gq = l >> 4;

    const int row = wv*16 + li;
    const int nA = blk*32 + row;
    const int nc = (nA < NN) ? nA : NN - 1;
    const unsigned short* pH = hb + nc*HD + gq*8;
    float* pA = aggr + nc*HD + gq*8;

    f4 acc[8];
    #pragma unroll
    for (int f = 0; f < 8; ++f) { f4 z = {0.f,0.f,0.f,0.f}; acc[f] = z; }

    #pragma unroll
    for (int s = 0; s < 8; ++s) {
        bf8 breg[8];
        #pragma unroll
        for (int f = 0; f < 8; ++f) breg[f] = *(const bf8*)(pw + s*4096 + f*512 + l*8);
        bf8 a;
        if (s < 4) {
            a = *(const bf8*)(pH + s*32);
        } else {
            const float4 a0 = *(const float4*)(pA + (s-4)*32);
            const float4 a1 = *(const float4*)(pA + (s-4)*32 + 4);
            union { unsigned int u[4]; bf8 v; } pk;
            pk.u[0] = cvt2(a0.x, a0.y); pk.u[1] = cvt2(a0.z, a0.w);
            pk.u[2] = cvt2(a1.x, a1.y); pk.u[3] = cvt2(a1.z, a1.w);
            a = pk.v;
        }
        #pragma unroll
        for (int f = 0; f < 8; ++f)
            acc[f] = __builtin_amdgcn_mfma_f32_16x16x32_bf16(a, breg[f], acc[f], 0, 0, 0);
    }

    // zero aggr slices for next layer
    {
        const float4 z = {0.f,0.f,0.f,0.f};
        if (nA < NN) {
            #pragma unroll
            for (int s = 0; s < 4; ++s) { *(float4*)(pA + s*32) = z; *(float4*)(pA + s*32 + 4) = z; }
        }
    }

    // epilogue 1 -> p-space t1
    {
        float bb[8], gg[8], be[8];
        #pragma unroll
        for (int f = 0; f < 8; ++f) {
            const int n = f*16 + li;
            bb[f] = b1[n]; gg[f] = g1[n]; be[f] = be1[n];
        }
        float ps[4] = {0,0,0,0}, pq[4] = {0,0,0,0};
        #pragma unroll
        for (int f = 0; f < 8; ++f)
            #pragma unroll
            for (int r = 0; r < 4; ++r) {
                const float v = acc[f][r] + bb[f];
                acc[f][r] = v;
                ps[r] += v; pq[r] += v*v;
            }
        #pragma unroll
        for (int mm = 1; mm < 16; mm <<= 1)
            #pragma unroll
            for (int r = 0; r < 4; ++r) {
                ps[r] += __shfl_xor(ps[r], mm);
                pq[r] += __shfl_xor(pq[r], mm);
            }
        #pragma unroll
        for (int r = 0; r < 4; ++r) {
            const float mean = ps[r] * (1.f/HD);
            const float rstd = rsqrtf(pq[r]*(1.f/HD) - mean*mean + LNEPS);
            const int rw = wv*16 + gq*4 + r;
            float vv[8];
            #pragma unroll
            for (int f = 0; f < 8; ++f)
                vv[f] = fmaxf((acc[f][r] - mean)*rstd*gg[f] + be[f], 0.f);
            uint4 u;
            u.x = cvt2(vv[0], vv[1]); u.y = cvt2(vv[2], vv[3]);
            u.z = cvt2(vv[4], vv[5]); u.w = cvt2(vv[6], vv[7]);
            *(uint4*)(ldsb + ((rw*256 + li*16) ^ ((rw & 15) << 4))) = u;
        }
    }
    // wave-private rows: no barrier

    const unsigned short* pw2 = pw + 32768;
    f4 acc2[8];
    #pragma unroll
    for (int f = 0; f < 8; ++f) { f4 z = {0.f,0.f,0.f,0.f}; acc2[f] = z; }
    #pragma unroll
    for (int s = 0; s < 4; ++s) {
        bf8 breg[8];
        #pragma unroll
        for (int f = 0; f < 8; ++f) breg[f] = *(const bf8*)(pw2 + s*4096 + f*512 + l*8);
        const int ar = wv*16 + li;
        const bf8 a = *(const bf8*)(ldsb + ((ar*256 + s*64 + gq*16) ^ ((ar & 15) << 4)));
        #pragma unroll
        for (int f = 0; f < 8; ++f)
            acc2[f] = __builtin_amdgcn_mfma_f32_16x16x32_bf16(a, breg[f], acc2[f], 0, 0, 0);
    }

    // epilogue 2: LN -> relu -> nh = h + u (global h/hb + p-space LDS for y-GEMM)
    {
        float bb2[8], gg2[8], be2v[8];
        #pragma unroll
        for (int f = 0; f < 8; ++f) {
            const int n = f*16 + li;
            bb2[f] = b2[n]; gg2[f] = g2[n]; be2v[f] = be2[n];
        }
        float ps[4] = {0,0,0,0}, pq[4] = {0,0,0,0};
        #pragma unroll
        for (int f = 0; f < 8; ++f)
            #pragma unroll
            for (int r = 0; r < 4; ++r) {
                const float v = acc2[f][r] + bb2[f];
                acc2[f][r] = v;
                ps[r] += v; pq[r] += v*v;
            }
        #pragma unroll
        for (int mm = 1; mm < 16; mm <<= 1)
            #pragma unroll
            for (int r = 0; r < 4; ++r) {
                ps[r] += __shfl_xor(ps[r], mm);
                pq[r] += __shfl_xor(pq[r], mm);
            }
        #pragma unroll
        for (int r = 0; r < 4; ++r) {
            const int node = blk*32 + wv*16 + gq*4 + r;
            const float mean = ps[r] * (1.f/HD);
            const float rstd = rsqrtf(pq[r]*(1.f/HD) - mean*mean + LNEPS);
            const int rw = wv*16 + gq*4 + r;
            float nhv[8];
            if (node < NN) {
                #pragma unroll
                for (int f = 0; f < 8; ++f) {
                    const int n = f*16 + li;
                    float v = fmaxf((acc2[f][r] - mean)*rstd*gg2[f] + be2v[f], 0.f);
                    const int idx = node*HD + n;
                    const float nh = h[idx] + v;
                    h[idx] = nh; hb[idx] = bf1(nh);
                    nhv[f] = nh;
                }
            } else {
                #pragma unroll
                for (int f = 0; f < 8; ++f) nhv[f] = 0.f;
            }
            uint4 u;
            u.x = cvt2(nhv[0], nhv[1]); u.y = cvt2(nhv[2], nhv[3]);
            u.z = cvt2(nhv[4], nhv[5]); u.w = cvt2(nhv[6], nhv[7]);
            *(uint4*)(ldsb + ((rw*256 + li*16) ^ ((rw & 15) << 4))) = u;
        }
    }

    // fused y-GEMM for next layer: A = nh p-space LDS, B = pinv-packed [W1d|W1s]
    if (do_y) {
        f4 accy[16];
        #pragma unroll
        for (int f = 0; f < 16; ++f) { f4 z = {0.f,0.f,0.f,0.f}; accy[f] = z; }
        #pragma unroll
        for (int s = 0; s < 4; ++s) {
            const int ar = wv*16 + li;
            const bf8 a = *(const bf8*)(ldsb + ((ar*256 + s*64 + gq*16) ^ ((ar & 15) << 4)));
            #pragma unroll
            for (int fh = 0; fh < 2; ++fh) {
                bf8 breg[8];
                #pragma unroll
                for (int f = 0; f < 8; ++f)
                    breg[f] = *(const bf8*)(pwy + s*8192 + (fh*8 + f)*512 + l*8);
                #pragma unroll
                for (int f = 0; f < 8; ++f)
                    accy[fh*8 + f] = __builtin_amdgcn_mfma_f32_16x16x32_bf16(a, breg[f], accy[fh*8 + f], 0, 0, 0);
            }
        }
        float bv[8];
        #pragma unroll
        for (int f = 0; f < 8; ++f) bv[f] = b1y[f*16 + li];
        #pragma unroll
        for (int r = 0; r < 4; ++r) {
            const int node = blk*32 + wv*16 + gq*4 + r;
            if (node < NN) {
                uint4 u;
                u.x = cvt2(accy[0][r]+bv[0], accy[1][r]+bv[1]);
                u.y = cvt2(accy[2][r]+bv[2], accy[3][r]+bv[3]);
                u.z = cvt2(accy[4][r]+bv[4], accy[5][r]+bv[5]);
                u.w = cvt2(accy[6][r]+bv[6], accy[7][r]+bv[7]);
                *(uint4*)(y + node*256 + li*8) = u;
                uint4 v;
                v.x = cvt2(accy[8][r],  accy[9][r]);
                v.y = cvt2(accy[10][r], accy[11][r]);
                v.z = cvt2(accy[12][r], accy[13][r]);
                v.w = cvt2(accy[14][r], accy[15][r]);
                *(uint4*)(y + node*256 + 128 + li*8) = v;
            }
        }
    }
}

// global_add_pool over sorted batch_ids
__global__ void pool_kernel(const float* __restrict__ h, const int* __restrict__ bids,
                            float* __restrict__ pooled) {
    const int j = threadIdx.x;                  // 128 features
    const int n0 = blockIdx.x * 256;
    if (n0 >= NN) return;
    int cur = bids[n0];
    float acc = 0.f;
    for (int i = 0; i < 256; ++i) {
        const int n = n0 + i;
        if (n >= NN) break;
        const int b = bids[n];
        if (b != cur) { unsafeAtomicAdd(&pooled[cur*HD + j], acc); acc = 0.f; cur = b; }
        acc += h[n*HD + j];
    }
    unsafeAtomicAdd(&pooled[cur*HD + j], acc);
}

__global__ void pred_kernel(const float* __restrict__ pooled, const float* __restrict__ w1,
                            const float* __restrict__ pb1, const float* __restrict__ w2,
                            const float* __restrict__ pb2, float* __restrict__ out) {
    const int g = blockIdx.x, j = threadIdx.x;  // 128 threads
    __shared__ float pg[128];
    __shared__ float red[128];
    pg[j] = pooled[g*HD + j];
    __syncthreads();
    float z = pb1[j];
    for (int k = 0; k < 128; ++k) z += pg[k] * w1[k*HD + j];
    red[j] = fmaxf(z, 0.f) * w2[j];
    __syncthreads();
    for (int st = 64; st > 0; st >>= 1) {
        if (j < st) red[j] += red[j + st];
        __syncthreads();
    }
    if (j == 0) out[g] = red[0] + pb2[0];
}

extern "C" void kernel_launch(void* const* d_in, const int* in_sizes, int n_in,
                              void* d_out, int out_size, void* d_ws, size_t ws_size,
                              hipStream_t stream) {
    const float* x       = (const float*)d_in[0];
    const float* pos     = (const float*)d_in[1];
    const int*   ei      = (const int*)  d_in[2];
    const float* cell    = (const float*)d_in[3];
    const float* U       = (const float*)d_in[4];
    const int*   bids    = (const int*)  d_in[5];
    const float* emb_w   = (const float*)d_in[6];
    const float* emb_b   = (const float*)d_in[7];
    const float* msg_w1  = (const float*)d_in[8];
    const float* msg_b1  = (const float*)d_in[9];
    const float* msg_g1  = (const float*)d_in[10];
    const float* msg_be1 = (const float*)d_in[11];
    const float* msg_w2  = (const float*)d_in[12];
    const float* msg_b2  = (const float*)d_in[13];
    const float* msg_g2  = (const float*)d_in[14];
    const float* msg_be2 = (const float*)d_in[15];
    const float* upd_w1  = (const float*)d_in[16];
    const float* upd_b1  = (const float*)d_in[17];
    const float* upd_g1  = (const float*)d_in[18];
    const float* upd_be1 = (const float*)d_in[19];
    const float* upd_w2  = (const float*)d_in[20];
    const float* upd_b2  = (const float*)d_in[21];
    const float* upd_g2  = (const float*)d_in[22];
    const float* upd_be2 = (const float*)d_in[23];
    const float* pred_w1 = (const float*)d_in[24];
    const float* pred_b1 = (const float*)d_in[25];
    const float* pred_w2 = (const float*)d_in[26];
    const float* pred_b2 = (const float*)d_in[27];

    char* ws = (char*)d_ws;
    float*          h      = (float*)          ws;                 // 25,600,000
    unsigned short* hb     = (unsigned short*)(ws + 25600000);     // 12,800,000
    float*          aggr   = (float*)         (ws + 38400000);     // 25,600,000
    float*          dist   = (float*)         (ws + 64000000);     //  3,200,000
    float*          pooled = (float*)         (ws + 67200000);     //     32,768
    unsigned short* packed = (unsigned short*)(ws + 67232768);     //    983,040
    int*            cnt    = (int*)           (ws + 68215808);     //    200,704
    int*            cur    = (int*)           (ws + 68416512);     //    200,704
    int*            sidx   = (int*)           (ws + 68617216);     //  3,200,000
    int*            ssrc   = (int*)           (ws + 71817216);     //  3,200,000
    int*            sdst   = (int*)           (ws + 75017216);     //  3,200,000
    float*          sig    = (float*)         (ws + 78217216);     //      7,680
    float*          y0ab   = (float*)         (ws + 78224896);     //      2,048
    unsigned short* y      = (unsigned short*)(ws + 78226944);     // 25,600,000

    hipMemsetAsync(aggr, 0, (size_t)NN * HD * sizeof(float), stream);
    hipMemsetAsync(pooled, 0, (size_t)NG * HD * sizeof(float), stream);
    hipMemsetAsync(cnt, 0, (size_t)NN * sizeof(int), stream);

    dim3 pgrid(128, DEPTH * 4);
    pack_weights<<<pgrid, 256, 0, stream>>>(msg_w1, msg_w2, upd_w1, upd_w2, packed);
    pack_sig<<<(DEPTH*384 + 255)/256, 256, 0, stream>>>(msg_w1, msg_g1, msg_be1, sig);
    pack_y0<<<1, 256, 0, stream>>>(emb_w, emb_b, msg_w1, msg_b1, y0ab);
    embed_kernel<<<NN, 256, 0, stream>>>(x, emb_w, emb_b, y0ab, h, hb, y);

    hist_kernel<<<NE / 256, 256, 0, stream>>>(ei, cnt);
    scan_kernel<<<1, 1024, 0, stream>>>(cnt, cur);
    scatter_kernel<<<NE / 256, 256, 0, stream>>>(ei, cur, sidx, ssrc, sdst);
    dist_kernel<<<NE / 256, 256, 0, stream>>>(pos, sidx, ssrc, sdst, cell, U, dist);

    for (int layer = 0; layer < DEPTH; ++layer) {
        const unsigned short* pl = packed + layer * 98304;
        edge_kernel<<<NE / 64, 128, 0, stream>>>(
            y, dist, ssrc, sdst, pl + 32768, sig + layer*384,
            msg_b2 + layer*HD, msg_g2 + layer*HD, msg_be2 + layer*HD,
            aggr);
        const int do_y = (layer + 1 < DEPTH) ? 1 : 0;
        const int nl = do_y ? layer + 1 : layer;
        node_kernel<<<(NN + 31) / 32, 128, 0, stream>>>(
            hb, aggr, pl + 49152,
            upd_b1 + layer*HD, upd_g1 + layer*HD, upd_be1 + layer*HD,
            upd_b2 + layer*HD, upd_g2 + layer*HD, upd_be2 + layer*HD,
            h,
            packed + nl * 98304, msg_b1 + nl*HD, y, do_y);
    }

    pool_kernel<<<(NN + 255) / 256, 128, 0, stream>>>(h, bids, pooled);
    pred_kernel<<<NG, 128, 0, stream>>>(pooled, pred_w1, pred_b1, pred_w2, pred_b2, (float*)d_out);
}